// Round 8
// baseline (3328.715 us; speedup 1.0000x reference)
//
#include <hip/hip_runtime.h>
#include <hip/hip_bf16.h>

#define DEVFN __device__ __forceinline__

// ---------------- debug signal ----------------
__global__ void k_signal(float* out, float v) {
    if (threadIdx.x == 0 && blockIdx.x == 0) out[0] = v;
}

// ---------------- int-width detect + normalize ----------------
__global__ void k_detect64(const long long* __restrict__ p, int count, int* flag) {
    if (threadIdx.x == 0 && blockIdx.x == 0) {
        int ok = 1;
        for (int i = 0; i < count; i++) {
            long long v = p[i];
            if (v < 0 || v >= (1LL << 30)) { ok = 0; break; }
        }
        *flag = ok;
    }
}

__global__ __launch_bounds__(256) void k_cvt_idx(const void* __restrict__ p, int n,
                                                 const int* __restrict__ flag,
                                                 int* __restrict__ out) {
    int i = blockIdx.x * 256 + threadIdx.x;
    if (i >= n) return;
    if (*flag) out[i] = (int)((const long long*)p)[i];
    else       out[i] = ((const int*)p)[i];
}

// ---------------- FC1: h1 = relu(x @ w1 + b1), (128,128)@(128,512) ----------------
__global__ __launch_bounds__(256) void k_fc1(const float* __restrict__ x,
                                             const float* __restrict__ w,
                                             const float* __restrict__ b,
                                             float* __restrict__ out) {
    int j = blockIdx.x * 256 + threadIdx.x;   // 512
    int m = blockIdx.y;                       // 128
    float acc = b[j];
    const float* xr = x + m * 128;
    for (int k = 0; k < 128; k++)
        acc = fmaf(xr[k], w[k * 512 + j], acc);
    out[m * 512 + j] = fmaxf(acc, 0.f);
}

// ---------------- FC2 GEMM v2: (128,512)@(512,110592)+b ----------------
// lane = column (64 consecutive cols per wave -> 256 B/instr coalescing);
// A-loads are block-uniform -> scalar-promoted. thread: 32 rows x 1 col.
__global__ __launch_bounds__(256) void k_fc2_gemm2(const float* __restrict__ h1,
                                                   const float* __restrict__ w,
                                                   const float* __restrict__ bias,
                                                   float* __restrict__ out) {
    const int N = 110592, K = 512;
    const int j  = blockIdx.x * 256 + threadIdx.x;  // column
    const int m0 = blockIdx.y * 32;                 // row base

    float acc[32];
    float bj = bias[j];
#pragma unroll
    for (int r = 0; r < 32; r++) acc[r] = bj;

    for (int k = 0; k < K; k += 4) {
        float wv[4];
#pragma unroll
        for (int kk = 0; kk < 4; kk++)
            wv[kk] = w[(size_t)(k + kk) * N + j];
#pragma unroll
        for (int r = 0; r < 32; r++) {
            float4 a = *(const float4*)(h1 + (m0 + r) * K + k);  // uniform
            acc[r] = fmaf(a.x, wv[0], acc[r]);
            acc[r] = fmaf(a.y, wv[1], acc[r]);
            acc[r] = fmaf(a.z, wv[2], acc[r]);
            acc[r] = fmaf(a.w, wv[3], acc[r]);
        }
    }
#pragma unroll
    for (int r = 0; r < 32; r++)
        out[(size_t)(m0 + r) * N + j] = acc[r];
}

// ---------------- graph build ----------------
__global__ __launch_bounds__(256) void k_zero_int(int* p, int n) {
    int i = blockIdx.x * 256 + threadIdx.x;
    if (i < n) p[i] = 0;
}

__global__ __launch_bounds__(256) void k_deg(const int* __restrict__ dst, int e,
                                             int* __restrict__ deg) {
    int i = blockIdx.x * 256 + threadIdx.x;
    if (i < e) atomicAdd(&deg[dst[i]], 1);
}

__global__ __launch_bounds__(256) void k_dinv(const int* __restrict__ deg,
                                              float* __restrict__ dinv, int n) {
    int i = blockIdx.x * 256 + threadIdx.x;
    if (i < n) dinv[i] = deg[i] > 0 ? 1.0f / sqrtf((float)deg[i]) : 0.0f;
}

// exclusive scan of deg[0..n) -> row_ptr[0..n], single block of 256 threads
__global__ __launch_bounds__(256) void k_scan(const int* __restrict__ deg,
                                              int* __restrict__ row_ptr, int n) {
    __shared__ int part[256];
    int tid = threadIdx.x;
    int per = (n + 255) / 256;
    int start = tid * per;
    int end = min(start + per, n);
    int s = 0;
    for (int i = start; i < end; i++) s += deg[i];
    part[tid] = s;
    __syncthreads();
    for (int off = 1; off < 256; off <<= 1) {
        int t = (tid >= off) ? part[tid - off] : 0;
        __syncthreads();
        part[tid] += t;
        __syncthreads();
    }
    int base = (tid == 0) ? 0 : part[tid - 1];
    int run = base;
    for (int i = start; i < end; i++) { row_ptr[i] = run; run += deg[i]; }
    if (tid == 255) row_ptr[n] = part[255];
}

__global__ __launch_bounds__(256) void k_fill(const int* __restrict__ src,
                                              const int* __restrict__ dst, int e,
                                              const int* __restrict__ row_ptr,
                                              int* __restrict__ cnt,
                                              const float* __restrict__ dinv,
                                              int* __restrict__ col, float* __restrict__ val) {
    int i = blockIdx.x * 256 + threadIdx.x;
    if (i >= e) return;
    int d = dst[i], s = src[i];
    int slot = row_ptr[d] + atomicAdd(&cnt[d], 1);
    col[slot] = s;
    val[slot] = -dinv[s] * dinv[d];
}

// ---------------- prop v2 (float4 channels): out[b,d,:] = sum val*h[b,col,:] ----------------
template <int CI, int MODE>
__global__ __launch_bounds__(256) void k_prop2(const float* __restrict__ h,
                                               const float* __restrict__ sub,
                                               const int* __restrict__ row_ptr,
                                               const int* __restrict__ col,
                                               const float* __restrict__ val,
                                               float* __restrict__ out, int n) {
    constexpr int C4 = CI / 4;
    constexpr int BY = 256 / C4;
    int c4 = threadIdx.x;
    int d = blockIdx.x;
    int b = blockIdx.y * BY + threadIdx.y;
    int p0 = row_ptr[d], p1 = row_ptr[d + 1];
    float4 acc = {0.f, 0.f, 0.f, 0.f};
    const float4* hb = (const float4*)h + (size_t)b * n * C4;
    for (int p = p0; p < p1; p++) {
        float vp = val[p];
        float4 hv = hb[(size_t)col[p] * C4 + c4];
        acc.x = fmaf(vp, hv.x, acc.x);
        acc.y = fmaf(vp, hv.y, acc.y);
        acc.z = fmaf(vp, hv.z, acc.z);
        acc.w = fmaf(vp, hv.w, acc.w);
    }
    size_t oi = ((size_t)b * n + d) * C4 + c4;
    if (MODE) {
        float4 s = ((const float4*)sub)[oi];
        acc.x = 2.f * acc.x - s.x;
        acc.y = 2.f * acc.y - s.y;
        acc.z = 2.f * acc.z - s.z;
        acc.w = 2.f * acc.w - s.w;
    }
    ((float4*)out)[oi] = acc;
}

// ---------------- cheb einsum GEMM v2 (wave-coalesced columns) ----------------
// lane covers CL consecutive cols; A-loads uniform within col-group.
// thread: RT rows x JT col-strips. + bias + lrelu + optional repeat.
template <int CI, int CO, bool REPEAT>
__global__ __launch_bounds__(256) void k_cheb_gemm2(const float* __restrict__ t0,
                                                    const float* __restrict__ t1,
                                                    const float* __restrict__ t2,
                                                    const float* __restrict__ W,
                                                    const float* __restrict__ bias,
                                                    float* __restrict__ out, int n) {
    constexpr int JT  = (CO > 64) ? 2 : 1;      // col strips per lane
    constexpr int CL  = (CO > 64) ? 64 : CO;    // col lanes
    constexpr int CPL = 64 / CL;                // row subgroups per wave
    constexpr int RT  = (CO == 64) ? 32 : 16;   // rows per thread
    constexpr int BLOCK_ROWS = 4 * CPL * RT;

    const int lane = threadIdx.x & 63;
    const int wid  = threadIdx.x >> 6;
    const int col  = lane % CL;
    const int rs   = lane / CL;
    const int m0   = blockIdx.x * BLOCK_ROWS + (wid * CPL + rs) * RT;

    float acc[RT][JT];
#pragma unroll
    for (int jj = 0; jj < JT; jj++) {
        float bj = bias[col + jj * 64];
#pragma unroll
        for (int r = 0; r < RT; r++) acc[r][jj] = bj;
    }

    const float* As[3] = {t0, t1, t2};
#pragma unroll 1
    for (int t = 0; t < 3; t++) {
        const float* A  = As[t] + (size_t)m0 * CI;
        const float* Wt = W + t * CI * CO;
        for (int k = 0; k < CI; k += 4) {
            float wv[4][JT];
#pragma unroll
            for (int kk = 0; kk < 4; kk++)
#pragma unroll
                for (int jj = 0; jj < JT; jj++)
                    wv[kk][jj] = Wt[(k + kk) * CO + col + jj * 64];
#pragma unroll
            for (int r = 0; r < RT; r++) {
                float4 a = *(const float4*)(A + r * CI + k);
#pragma unroll
                for (int jj = 0; jj < JT; jj++) {
                    acc[r][jj] = fmaf(a.x, wv[0][jj], acc[r][jj]);
                    acc[r][jj] = fmaf(a.y, wv[1][jj], acc[r][jj]);
                    acc[r][jj] = fmaf(a.z, wv[2][jj], acc[r][jj]);
                    acc[r][jj] = fmaf(a.w, wv[3][jj], acc[r][jj]);
                }
            }
        }
    }

#pragma unroll
    for (int r = 0; r < RT; r++) {
        int m = m0 + r;
        size_t o0;
        if (REPEAT) {
            int b = m / n, d = m - (m / n) * n;
            o0 = ((size_t)b * (2 * n) + 2 * d) * CO;
        } else {
            o0 = (size_t)m * CO;
        }
#pragma unroll
        for (int jj = 0; jj < JT; jj++) {
            float v = acc[r][jj];
            v = v >= 0.f ? v : 0.2f * v;   // lrelu (layers 0-3 all use it)
            int j = col + jj * 64;
            out[o0 + j] = v;
            if (REPEAT) out[o0 + CO + j] = v;
        }
    }
}

// ---------------- final conv: ci=16, co=3, no lrelu/repeat ----------------
__global__ __launch_bounds__(256) void k_final_conv(const float* __restrict__ t0,
                                                    const float* __restrict__ t1,
                                                    const float* __restrict__ t2,
                                                    const float* __restrict__ W,
                                                    const float* __restrict__ bias,
                                                    float* __restrict__ out, int M) {
    int m = blockIdx.x * 256 + threadIdx.x;
    if (m >= M) return;
    float a0 = bias[0], a1 = bias[1], a2 = bias[2];
    const float* hs[3] = {t0, t1, t2};
#pragma unroll
    for (int t = 0; t < 3; t++) {
        const float4* h4 = (const float4*)(hs[t] + (size_t)m * 16);
        const float* Wt = W + t * 48;
#pragma unroll
        for (int q = 0; q < 4; q++) {
            float4 hv = h4[q];
            const float* Wq = Wt + q * 12;
            a0 = fmaf(hv.x, Wq[0], a0); a1 = fmaf(hv.x, Wq[1], a1); a2 = fmaf(hv.x, Wq[2], a2);
            a0 = fmaf(hv.y, Wq[3], a0); a1 = fmaf(hv.y, Wq[4], a1); a2 = fmaf(hv.y, Wq[5], a2);
            a0 = fmaf(hv.z, Wq[6], a0); a1 = fmaf(hv.z, Wq[7], a1); a2 = fmaf(hv.z, Wq[8], a2);
            a0 = fmaf(hv.w, Wq[9], a0); a1 = fmaf(hv.w, Wq[10], a1); a2 = fmaf(hv.w, Wq[11], a2);
        }
    }
    out[(size_t)m * 3 + 0] = a0;
    out[(size_t)m * 3 + 1] = a1;
    out[(size_t)m * 3 + 2] = a2;
}

// ---------------- permute + slice (f32 output) ----------------
__global__ __launch_bounds__(256) void k_permute(const float* __restrict__ h,
                                                 const int* __restrict__ perm,
                                                 float* __restrict__ out) {
    const int V = 6890, N = 6912;
    int idx = blockIdx.x * 256 + threadIdx.x;
    if (idx >= 128 * V * 3) return;
    int c = idx % 3;
    int t = idx / 3;
    int v = t % V;
    int b = t / V;
    int p = perm[v];
    out[idx] = h[((size_t)b * N + p) * 3 + c];
}

extern "C" void kernel_launch(void* const* d_in, const int* in_sizes, int n_in,
                              void* d_out, int out_size, void* d_ws, size_t ws_size,
                              hipStream_t stream) {
    float* out = (float*)d_out;

    // ---- remap inputs by UNIQUE element counts (immune to input ordering) ----
    static const int SIZES[20] = {
        16384, 65536, 512, 56623104, 110592,
        49152, 128, 24576, 64, 6144, 32, 1536, 16, 144, 3,
        10368, 20736, 41472, 82944, 6912
    };
    const void* in[20];
    bool map_ok = (n_in == 20);
    if (map_ok) {
        for (int s = 0; s < 20; s++) {
            int found = -1;
            for (int i = 0; i < n_in; i++)
                if (in_sizes[i] == SIZES[s]) { found = i; break; }
            if (found < 0) { map_ok = false; break; }
            in[s] = d_in[found];
        }
    }
    if (!map_ok)
        for (int i = 0; i < 20 && i < n_in; i++) in[i] = d_in[i];

    const float* x     = (const float*)in[0];
    const float* fc_w1 = (const float*)in[1];
    const float* fc_b1 = (const float*)in[2];
    const float* fc_w2 = (const float*)in[3];
    const float* fc_b2 = (const float*)in[4];
    const float* W0 = (const float*)in[5];
    const float* b0 = (const float*)in[6];
    const float* W1 = (const float*)in[7];
    const float* b1 = (const float*)in[8];
    const float* W2 = (const float*)in[9];
    const float* b2 = (const float*)in[10];
    const float* W3 = (const float*)in[11];
    const float* b3 = (const float*)in[12];
    const float* W4 = (const float*)in[13];
    const float* b4 = (const float*)in[14];

    const size_t SZ = 28311552;  // 128*1728*128 max buffer elems
    float* ws = (float*)d_ws;
    float* buf0 = ws;
    float* buf1 = ws + SZ;
    float* buf2 = ws + 2 * SZ;
    float* buf3 = ws + 3 * SZ;
    float* h1   = ws + 4 * SZ;           // 65536
    float* dinv = h1 + 65536;            // 6912
    float* val  = dinv + 6912;           // 41472
    int* ideg = (int*)(val + 41472);     // 6912
    int* rowp = ideg + 6912;             // 6913
    int* cnt  = rowp + 6913;             // 6912
    int* col  = cnt + 6912;              // 41472
    int* e0 = col + 41472;               // 10368
    int* e1 = e0 + 10368;                // 20736
    int* e2 = e1 + 20736;                // 41472
    int* e3 = e2 + 41472;                // 82944
    int* pm = e3 + 82944;                // 6912
    int* flag = pm + 6912;               // 1
    size_t needed = (char*)(flag + 1) - (char*)d_ws;
    if (ws_size < needed) {
        k_signal<<<1, 64, 0, stream>>>(out, 1000.0f);
        return;
    }

    // --- normalize integer inputs (int64 vs int32, decided on device) ---
    k_detect64<<<1, 64, 0, stream>>>((const long long*)in[15], 64, flag);
    k_cvt_idx<<<(10368 + 255) / 256, 256, 0, stream>>>(in[15], 10368, flag, e0);
    k_cvt_idx<<<(20736 + 255) / 256, 256, 0, stream>>>(in[16], 20736, flag, e1);
    k_cvt_idx<<<(41472 + 255) / 256, 256, 0, stream>>>(in[17], 41472, flag, e2);
    k_cvt_idx<<<(82944 + 255) / 256, 256, 0, stream>>>(in[18], 82944, flag, e3);
    k_cvt_idx<<<(6912 + 255) / 256, 256, 0, stream>>>(in[19], 6912, flag, pm);

    // FC1 + FC2
    k_fc1<<<dim3(2, 128), 256, 0, stream>>>(x, fc_w1, fc_b1, h1);
    k_fc2_gemm2<<<dim3(432, 4), 256, 0, stream>>>(h1, fc_w2, fc_b2, buf0);

    auto build = [&](const int* edge, int e, int n) {
        int nb_n = (n + 255) / 256, nb_e = (e + 255) / 256;
        k_zero_int<<<nb_n, 256, 0, stream>>>(ideg, n);
        k_zero_int<<<nb_n, 256, 0, stream>>>(cnt, n);
        k_deg<<<nb_e, 256, 0, stream>>>(edge + e, e, ideg);
        k_dinv<<<nb_n, 256, 0, stream>>>(ideg, dinv, n);
        k_scan<<<1, 256, 0, stream>>>(ideg, rowp, n);
        k_fill<<<nb_e, 256, 0, stream>>>(edge, edge + e, e, rowp, cnt, dinv, col, val);
    };

    // Layer 0: n=864, ci=128, co=128, in buf0 -> out buf3 (repeated to n=1728)
    build(e0, 6 * 864, 864);
    k_prop2<128, 0><<<dim3(864, 16), dim3(32, 8), 0, stream>>>(buf0, buf0, rowp, col, val, buf1, 864);
    k_prop2<128, 1><<<dim3(864, 16), dim3(32, 8), 0, stream>>>(buf1, buf0, rowp, col, val, buf2, 864);
    k_cheb_gemm2<128, 128, true><<<1728, 256, 0, stream>>>(buf0, buf1, buf2, W0, b0, buf3, 864);

    // Layer 1: n=1728, ci=128, co=64, in buf3 -> out buf0 (repeated to 3456)
    build(e1, 6 * 1728, 1728);
    k_prop2<128, 0><<<dim3(1728, 16), dim3(32, 8), 0, stream>>>(buf3, buf3, rowp, col, val, buf1, 1728);
    k_prop2<128, 1><<<dim3(1728, 16), dim3(32, 8), 0, stream>>>(buf1, buf3, rowp, col, val, buf2, 1728);
    k_cheb_gemm2<128, 64, true><<<1728, 256, 0, stream>>>(buf3, buf1, buf2, W1, b1, buf0, 1728);

    // Layer 2: n=3456, ci=64, co=32, in buf0 -> out buf3 (repeated to 6912)
    build(e2, 6 * 3456, 3456);
    k_prop2<64, 0><<<dim3(3456, 8), dim3(16, 16), 0, stream>>>(buf0, buf0, rowp, col, val, buf1, 3456);
    k_prop2<64, 1><<<dim3(3456, 8), dim3(16, 16), 0, stream>>>(buf1, buf0, rowp, col, val, buf2, 3456);
    k_cheb_gemm2<64, 32, true><<<3456, 256, 0, stream>>>(buf0, buf1, buf2, W2, b2, buf3, 3456);

    // Layer 3: n=6912, ci=32, co=16, lrelu but NO repeat (i<3 only)
    build(e3, 6 * 6912, 6912);
    k_prop2<32, 0><<<dim3(6912, 4), dim3(8, 32), 0, stream>>>(buf3, buf3, rowp, col, val, buf1, 6912);
    k_prop2<32, 1><<<dim3(6912, 4), dim3(8, 32), 0, stream>>>(buf1, buf3, rowp, col, val, buf2, 6912);
    k_cheb_gemm2<32, 16, false><<<3456, 256, 0, stream>>>(buf3, buf1, buf2, W3, b3, buf0, 6912);

    // Layer 4: n=6912, ci=16, co=3, reuse CSR of edge3
    k_prop2<16, 0><<<dim3(6912, 2), dim3(4, 64), 0, stream>>>(buf0, buf0, rowp, col, val, buf1, 6912);
    k_prop2<16, 1><<<dim3(6912, 2), dim3(4, 64), 0, stream>>>(buf1, buf0, rowp, col, val, buf2, 6912);
    k_final_conv<<<(884736 + 255) / 256, 256, 0, stream>>>(buf0, buf1, buf2, W4, b4, buf3, 884736);

    // Permute + slice, f32 output
    int tot = 128 * 6890 * 3;
    k_permute<<<(tot + 255) / 256, 256, 0, stream>>>(buf3, pm, out);

    if (!map_ok) k_signal<<<1, 64, 0, stream>>>(out, 2000.0f);
}

// Round 9
// 2174.824 us; speedup vs baseline: 1.5306x; 1.5306x over previous
//
#include <hip/hip_runtime.h>
#include <hip/hip_bf16.h>

#define DEVFN __device__ __forceinline__

// ---------------- debug signal ----------------
__global__ void k_signal(float* out, float v) {
    if (threadIdx.x == 0 && blockIdx.x == 0) out[0] = v;
}

// ---------------- int-width detect + normalize ----------------
__global__ void k_detect64(const long long* __restrict__ p, int count, int* flag) {
    if (threadIdx.x == 0 && blockIdx.x == 0) {
        int ok = 1;
        for (int i = 0; i < count; i++) {
            long long v = p[i];
            if (v < 0 || v >= (1LL << 30)) { ok = 0; break; }
        }
        *flag = ok;
    }
}

__global__ __launch_bounds__(256) void k_cvt_idx(const void* __restrict__ p, int n,
                                                 const int* __restrict__ flag,
                                                 int* __restrict__ out) {
    int i = blockIdx.x * 256 + threadIdx.x;
    if (i >= n) return;
    if (*flag) out[i] = (int)((const long long*)p)[i];
    else       out[i] = ((const int*)p)[i];
}

// ---------------- FC1: h1 = relu(x @ w1 + b1), (128,128)@(128,512) ----------------
__global__ __launch_bounds__(256) void k_fc1(const float* __restrict__ x,
                                             const float* __restrict__ w,
                                             const float* __restrict__ b,
                                             float* __restrict__ out) {
    int j = blockIdx.x * 256 + threadIdx.x;   // 512
    int m = blockIdx.y;                       // 128
    float acc = b[j];
    const float* xr = x + m * 128;
    for (int k = 0; k < 128; k++)
        acc = fmaf(xr[k], w[k * 512 + j], acc);
    out[m * 512 + j] = fmaxf(acc, 0.f);
}

// ---------------- FC2 LDS-tiled GEMM: C[128,110592] = h1[128,512] @ w2 + b ----------------
// Block: 128 rows x 64 cols. Thread: 4 rows x 8 cols. K chunked by 32, staged in LDS.
__global__ __launch_bounds__(256) void k_fc2_gemm3(const float* __restrict__ h1,
                                                   const float* __restrict__ w,
                                                   const float* __restrict__ bias,
                                                   float* __restrict__ out) {
    const int N = 110592, K = 512;
    constexpr int KT = 32, MT = 128, NT = 64, AST = 37;  // AST: padded A row stride
    __shared__ float At[MT * AST];     // A-tile [row][k], stride 37 (bank-spread)
    __shared__ float Bt[KT * NT];      // B-tile [k][col]

    const int tid = threadIdx.x;
    const int cg = tid & 7;            // 8 col-groups of 8
    const int rg = tid >> 3;           // 32 row-groups of 4
    const int nbase = blockIdx.x * NT;
    const int c0 = cg * 8;

    float acc[4][8];
#pragma unroll
    for (int jj = 0; jj < 8; jj++) {
        float bj = bias[nbase + c0 + jj];
#pragma unroll
        for (int r = 0; r < 4; r++) acc[r][jj] = bj;
    }

    for (int k0 = 0; k0 < K; k0 += KT) {
        __syncthreads();
        // load A chunk: 128 rows x 32 k  (1024 float4, 4 per thread)
#pragma unroll
        for (int it = 0; it < 4; it++) {
            int idx = tid + it * 256;
            int row = idx >> 3, k4 = (idx & 7) * 4;
            float4 a = *(const float4*)(h1 + row * K + k0 + k4);
            float* dst = At + row * AST + k4;
            dst[0] = a.x; dst[1] = a.y; dst[2] = a.z; dst[3] = a.w;
        }
        // load B chunk: 32 k x 64 cols (512 float4, 2 per thread)
#pragma unroll
        for (int it = 0; it < 2; it++) {
            int idx = tid + it * 256;
            int kk = idx >> 4, c4 = (idx & 15) * 4;
            *(float4*)(Bt + kk * NT + c4) =
                *(const float4*)(w + (size_t)(k0 + kk) * N + nbase + c4);
        }
        __syncthreads();
#pragma unroll 4
        for (int k = 0; k < KT; k++) {
            float a0 = At[(rg * 4 + 0) * AST + k];
            float a1 = At[(rg * 4 + 1) * AST + k];
            float a2 = At[(rg * 4 + 2) * AST + k];
            float a3 = At[(rg * 4 + 3) * AST + k];
            float4 w0 = *(const float4*)(Bt + k * NT + c0);
            float4 w1 = *(const float4*)(Bt + k * NT + c0 + 4);
            float wv[8] = {w0.x, w0.y, w0.z, w0.w, w1.x, w1.y, w1.z, w1.w};
#pragma unroll
            for (int jj = 0; jj < 8; jj++) {
                acc[0][jj] = fmaf(a0, wv[jj], acc[0][jj]);
                acc[1][jj] = fmaf(a1, wv[jj], acc[1][jj]);
                acc[2][jj] = fmaf(a2, wv[jj], acc[2][jj]);
                acc[3][jj] = fmaf(a3, wv[jj], acc[3][jj]);
            }
        }
    }
#pragma unroll
    for (int r = 0; r < 4; r++) {
        int m = rg * 4 + r;
        float4 o0 = {acc[r][0], acc[r][1], acc[r][2], acc[r][3]};
        float4 o1 = {acc[r][4], acc[r][5], acc[r][6], acc[r][7]};
        *(float4*)(out + (size_t)m * N + nbase + c0) = o0;
        *(float4*)(out + (size_t)m * N + nbase + c0 + 4) = o1;
    }
}

// ---------------- graph build ----------------
__global__ __launch_bounds__(256) void k_zero_int(int* p, int n) {
    int i = blockIdx.x * 256 + threadIdx.x;
    if (i < n) p[i] = 0;
}

__global__ __launch_bounds__(256) void k_deg(const int* __restrict__ dst, int e,
                                             int* __restrict__ deg) {
    int i = blockIdx.x * 256 + threadIdx.x;
    if (i < e) atomicAdd(&deg[dst[i]], 1);
}

__global__ __launch_bounds__(256) void k_dinv(const int* __restrict__ deg,
                                              float* __restrict__ dinv, int n) {
    int i = blockIdx.x * 256 + threadIdx.x;
    if (i < n) dinv[i] = deg[i] > 0 ? 1.0f / sqrtf((float)deg[i]) : 0.0f;
}

// exclusive scan of deg[0..n) -> row_ptr[0..n], single block of 256 threads
__global__ __launch_bounds__(256) void k_scan(const int* __restrict__ deg,
                                              int* __restrict__ row_ptr, int n) {
    __shared__ int part[256];
    int tid = threadIdx.x;
    int per = (n + 255) / 256;
    int start = tid * per;
    int end = min(start + per, n);
    int s = 0;
    for (int i = start; i < end; i++) s += deg[i];
    part[tid] = s;
    __syncthreads();
    for (int off = 1; off < 256; off <<= 1) {
        int t = (tid >= off) ? part[tid - off] : 0;
        __syncthreads();
        part[tid] += t;
        __syncthreads();
    }
    int base = (tid == 0) ? 0 : part[tid - 1];
    int run = base;
    for (int i = start; i < end; i++) { row_ptr[i] = run; run += deg[i]; }
    if (tid == 255) row_ptr[n] = part[255];
}

__global__ __launch_bounds__(256) void k_fill(const int* __restrict__ src,
                                              const int* __restrict__ dst, int e,
                                              const int* __restrict__ row_ptr,
                                              int* __restrict__ cnt,
                                              const float* __restrict__ dinv,
                                              int* __restrict__ col, float* __restrict__ val) {
    int i = blockIdx.x * 256 + threadIdx.x;
    if (i >= e) return;
    int d = dst[i], s = src[i];
    int slot = row_ptr[d] + atomicAdd(&cnt[d], 1);
    col[slot] = s;
    val[slot] = -dinv[s] * dinv[d];
}

// ---------------- prop v2 (float4 channels) ----------------
template <int CI, int MODE>
__global__ __launch_bounds__(256) void k_prop2(const float* __restrict__ h,
                                               const float* __restrict__ sub,
                                               const int* __restrict__ row_ptr,
                                               const int* __restrict__ col,
                                               const float* __restrict__ val,
                                               float* __restrict__ out, int n) {
    constexpr int C4 = CI / 4;
    constexpr int BY = 256 / C4;
    int c4 = threadIdx.x;
    int d = blockIdx.x;
    int b = blockIdx.y * BY + threadIdx.y;
    int p0 = row_ptr[d], p1 = row_ptr[d + 1];
    float4 acc = {0.f, 0.f, 0.f, 0.f};
    const float4* hb = (const float4*)h + (size_t)b * n * C4;
    for (int p = p0; p < p1; p++) {
        float vp = val[p];
        float4 hv = hb[(size_t)col[p] * C4 + c4];
        acc.x = fmaf(vp, hv.x, acc.x);
        acc.y = fmaf(vp, hv.y, acc.y);
        acc.z = fmaf(vp, hv.z, acc.z);
        acc.w = fmaf(vp, hv.w, acc.w);
    }
    size_t oi = ((size_t)b * n + d) * C4 + c4;
    if (MODE) {
        float4 s = ((const float4*)sub)[oi];
        acc.x = 2.f * acc.x - s.x;
        acc.y = 2.f * acc.y - s.y;
        acc.z = 2.f * acc.z - s.z;
        acc.w = 2.f * acc.w - s.w;
    }
    ((float4*)out)[oi] = acc;
}

// ---------------- cheb einsum GEMM v3 (LDS-tiled) ----------------
// C[M,CO] = sum_t Tt[M,CI]@Wt + bias, lrelu, optional repeat.
// Block: MT rows x CO cols, MT = 1024/(CO/8). Thread: 4 rows x 8 cols.
template <int CI, int CO, bool REPEAT>
__global__ __launch_bounds__(256) void k_cheb_gemm3(const float* __restrict__ t0,
                                                    const float* __restrict__ t1,
                                                    const float* __restrict__ t2,
                                                    const float* __restrict__ W,
                                                    const float* __restrict__ bias,
                                                    float* __restrict__ out, int n) {
    constexpr int CGN = CO / 8;         // col-groups
    constexpr int MT = 1024 / CGN;      // rows per block (CO=128:64, 64:128, 32:256)
    constexpr int KT = 32, AST = 37;
    __shared__ float At[MT * AST];
    __shared__ float Wt_s[KT * CO];

    const int tid = threadIdx.x;
    const int cg = tid % CGN;
    const int rg = tid / CGN;
    const int m_base = blockIdx.x * MT;
    const int c0 = cg * 8;

    float acc[4][8];
#pragma unroll
    for (int jj = 0; jj < 8; jj++) {
        float bj = bias[c0 + jj];
#pragma unroll
        for (int r = 0; r < 4; r++) acc[r][jj] = bj;
    }

    const float* As[3] = {t0, t1, t2};
#pragma unroll 1
    for (int t = 0; t < 3; t++) {
        const float* A = As[t];
        const float* Wg = W + t * CI * CO;
#pragma unroll 1
        for (int k0 = 0; k0 < CI; k0 += KT) {
            __syncthreads();
            // A chunk: MT rows x 32 k  (MT*8 float4)
#pragma unroll
            for (int it = 0; it < MT / 32; it++) {
                int idx = tid + it * 256;
                int row = idx >> 3, k4 = (idx & 7) * 4;
                float4 a = *(const float4*)(A + (size_t)(m_base + row) * CI + k0 + k4);
                float* dst = At + row * AST + k4;
                dst[0] = a.x; dst[1] = a.y; dst[2] = a.z; dst[3] = a.w;
            }
            // W chunk: 32 k x CO
#pragma unroll
            for (int it = 0; it < (KT * CO) / 1024; it++) {
                int idx = tid + it * 256;
                int kk = idx / (CO / 4), c4 = (idx % (CO / 4)) * 4;
                *(float4*)(Wt_s + kk * CO + c4) =
                    *(const float4*)(Wg + (k0 + kk) * CO + c4);
            }
            __syncthreads();
#pragma unroll 4
            for (int k = 0; k < KT; k++) {
                float a0 = At[(rg * 4 + 0) * AST + k];
                float a1 = At[(rg * 4 + 1) * AST + k];
                float a2 = At[(rg * 4 + 2) * AST + k];
                float a3 = At[(rg * 4 + 3) * AST + k];
                float4 w0 = *(const float4*)(Wt_s + k * CO + c0);
                float4 w1 = *(const float4*)(Wt_s + k * CO + c0 + 4);
                float wv[8] = {w0.x, w0.y, w0.z, w0.w, w1.x, w1.y, w1.z, w1.w};
#pragma unroll
                for (int jj = 0; jj < 8; jj++) {
                    acc[0][jj] = fmaf(a0, wv[jj], acc[0][jj]);
                    acc[1][jj] = fmaf(a1, wv[jj], acc[1][jj]);
                    acc[2][jj] = fmaf(a2, wv[jj], acc[2][jj]);
                    acc[3][jj] = fmaf(a3, wv[jj], acc[3][jj]);
                }
            }
        }
    }

#pragma unroll
    for (int r = 0; r < 4; r++) {
        int m = m_base + rg * 4 + r;
#pragma unroll
        for (int jj = 0; jj < 8; jj++) {
            float v = acc[r][jj];
            acc[r][jj] = v >= 0.f ? v : 0.2f * v;   // lrelu
        }
        float4 o0 = {acc[r][0], acc[r][1], acc[r][2], acc[r][3]};
        float4 o1 = {acc[r][4], acc[r][5], acc[r][6], acc[r][7]};
        if (REPEAT) {
            int b = m / n, d = m - (m / n) * n;
            size_t ob = ((size_t)b * (2 * n) + 2 * d) * CO + c0;
            *(float4*)(out + ob) = o0;
            *(float4*)(out + ob + 4) = o1;
            *(float4*)(out + ob + CO) = o0;
            *(float4*)(out + ob + CO + 4) = o1;
        } else {
            *(float4*)(out + (size_t)m * CO + c0) = o0;
            *(float4*)(out + (size_t)m * CO + c0 + 4) = o1;
        }
    }
}

// ---------------- cheb einsum v2 (kept for CO=16 layer 3) ----------------
template <int CI, int CO, bool REPEAT>
__global__ __launch_bounds__(256) void k_cheb_gemm2(const float* __restrict__ t0,
                                                    const float* __restrict__ t1,
                                                    const float* __restrict__ t2,
                                                    const float* __restrict__ W,
                                                    const float* __restrict__ bias,
                                                    float* __restrict__ out, int n) {
    constexpr int JT  = (CO > 64) ? 2 : 1;
    constexpr int CL  = (CO > 64) ? 64 : CO;
    constexpr int CPL = 64 / CL;
    constexpr int RT  = (CO == 64) ? 32 : 16;
    constexpr int BLOCK_ROWS = 4 * CPL * RT;

    const int lane = threadIdx.x & 63;
    const int wid  = threadIdx.x >> 6;
    const int col  = lane % CL;
    const int rs   = lane / CL;
    const int m0   = blockIdx.x * BLOCK_ROWS + (wid * CPL + rs) * RT;

    float acc[RT][JT];
#pragma unroll
    for (int jj = 0; jj < JT; jj++) {
        float bj = bias[col + jj * 64];
#pragma unroll
        for (int r = 0; r < RT; r++) acc[r][jj] = bj;
    }

    const float* As[3] = {t0, t1, t2};
#pragma unroll 1
    for (int t = 0; t < 3; t++) {
        const float* A  = As[t] + (size_t)m0 * CI;
        const float* Wt = W + t * CI * CO;
        for (int k = 0; k < CI; k += 4) {
            float wv[4][JT];
#pragma unroll
            for (int kk = 0; kk < 4; kk++)
#pragma unroll
                for (int jj = 0; jj < JT; jj++)
                    wv[kk][jj] = Wt[(k + kk) * CO + col + jj * 64];
#pragma unroll
            for (int r = 0; r < RT; r++) {
                float4 a = *(const float4*)(A + r * CI + k);
#pragma unroll
                for (int jj = 0; jj < JT; jj++) {
                    acc[r][jj] = fmaf(a.x, wv[0][jj], acc[r][jj]);
                    acc[r][jj] = fmaf(a.y, wv[1][jj], acc[r][jj]);
                    acc[r][jj] = fmaf(a.z, wv[2][jj], acc[r][jj]);
                    acc[r][jj] = fmaf(a.w, wv[3][jj], acc[r][jj]);
                }
            }
        }
    }

#pragma unroll
    for (int r = 0; r < RT; r++) {
        int m = m0 + r;
        size_t o0;
        if (REPEAT) {
            int b = m / n, d = m - (m / n) * n;
            o0 = ((size_t)b * (2 * n) + 2 * d) * CO;
        } else {
            o0 = (size_t)m * CO;
        }
#pragma unroll
        for (int jj = 0; jj < JT; jj++) {
            float v = acc[r][jj];
            v = v >= 0.f ? v : 0.2f * v;
            int j = col + jj * 64;
            out[o0 + j] = v;
            if (REPEAT) out[o0 + CO + j] = v;
        }
    }
}

// ---------------- final conv: ci=16, co=3 ----------------
__global__ __launch_bounds__(256) void k_final_conv(const float* __restrict__ t0,
                                                    const float* __restrict__ t1,
                                                    const float* __restrict__ t2,
                                                    const float* __restrict__ W,
                                                    const float* __restrict__ bias,
                                                    float* __restrict__ out, int M) {
    int m = blockIdx.x * 256 + threadIdx.x;
    if (m >= M) return;
    float a0 = bias[0], a1 = bias[1], a2 = bias[2];
    const float* hs[3] = {t0, t1, t2};
#pragma unroll
    for (int t = 0; t < 3; t++) {
        const float4* h4 = (const float4*)(hs[t] + (size_t)m * 16);
        const float* Wt = W + t * 48;
#pragma unroll
        for (int q = 0; q < 4; q++) {
            float4 hv = h4[q];
            const float* Wq = Wt + q * 12;
            a0 = fmaf(hv.x, Wq[0], a0); a1 = fmaf(hv.x, Wq[1], a1); a2 = fmaf(hv.x, Wq[2], a2);
            a0 = fmaf(hv.y, Wq[3], a0); a1 = fmaf(hv.y, Wq[4], a1); a2 = fmaf(hv.y, Wq[5], a2);
            a0 = fmaf(hv.z, Wq[6], a0); a1 = fmaf(hv.z, Wq[7], a1); a2 = fmaf(hv.z, Wq[8], a2);
            a0 = fmaf(hv.w, Wq[9], a0); a1 = fmaf(hv.w, Wq[10], a1); a2 = fmaf(hv.w, Wq[11], a2);
        }
    }
    out[(size_t)m * 3 + 0] = a0;
    out[(size_t)m * 3 + 1] = a1;
    out[(size_t)m * 3 + 2] = a2;
}

// ---------------- permute + slice (f32 output) ----------------
__global__ __launch_bounds__(256) void k_permute(const float* __restrict__ h,
                                                 const int* __restrict__ perm,
                                                 float* __restrict__ out) {
    const int V = 6890, N = 6912;
    int idx = blockIdx.x * 256 + threadIdx.x;
    if (idx >= 128 * V * 3) return;
    int c = idx % 3;
    int t = idx / 3;
    int v = t % V;
    int b = t / V;
    int p = perm[v];
    out[idx] = h[((size_t)b * N + p) * 3 + c];
}

extern "C" void kernel_launch(void* const* d_in, const int* in_sizes, int n_in,
                              void* d_out, int out_size, void* d_ws, size_t ws_size,
                              hipStream_t stream) {
    float* out = (float*)d_out;

    static const int SIZES[20] = {
        16384, 65536, 512, 56623104, 110592,
        49152, 128, 24576, 64, 6144, 32, 1536, 16, 144, 3,
        10368, 20736, 41472, 82944, 6912
    };
    const void* in[20];
    bool map_ok = (n_in == 20);
    if (map_ok) {
        for (int s = 0; s < 20; s++) {
            int found = -1;
            for (int i = 0; i < n_in; i++)
                if (in_sizes[i] == SIZES[s]) { found = i; break; }
            if (found < 0) { map_ok = false; break; }
            in[s] = d_in[found];
        }
    }
    if (!map_ok)
        for (int i = 0; i < 20 && i < n_in; i++) in[i] = d_in[i];

    const float* x     = (const float*)in[0];
    const float* fc_w1 = (const float*)in[1];
    const float* fc_b1 = (const float*)in[2];
    const float* fc_w2 = (const float*)in[3];
    const float* fc_b2 = (const float*)in[4];
    const float* W0 = (const float*)in[5];
    const float* b0 = (const float*)in[6];
    const float* W1 = (const float*)in[7];
    const float* b1 = (const float*)in[8];
    const float* W2 = (const float*)in[9];
    const float* b2 = (const float*)in[10];
    const float* W3 = (const float*)in[11];
    const float* b3 = (const float*)in[12];
    const float* W4 = (const float*)in[13];
    const float* b4 = (const float*)in[14];

    const size_t SZ = 28311552;  // 128*1728*128 max buffer elems
    float* ws = (float*)d_ws;
    float* buf0 = ws;
    float* buf1 = ws + SZ;
    float* buf2 = ws + 2 * SZ;
    float* buf3 = ws + 3 * SZ;
    float* h1   = ws + 4 * SZ;           // 65536
    float* dinv = h1 + 65536;            // 6912
    float* val  = dinv + 6912;           // 41472
    int* ideg = (int*)(val + 41472);     // 6912
    int* rowp = ideg + 6912;             // 6913
    int* cnt  = rowp + 6913;             // 6912
    int* col  = cnt + 6912;              // 41472
    int* e0 = col + 41472;               // 10368
    int* e1 = e0 + 10368;                // 20736
    int* e2 = e1 + 20736;                // 41472
    int* e3 = e2 + 41472;                // 82944
    int* pm = e3 + 82944;                // 6912
    int* flag = pm + 6912;               // 1
    size_t needed = (char*)(flag + 1) - (char*)d_ws;
    if (ws_size < needed) {
        k_signal<<<1, 64, 0, stream>>>(out, 1000.0f);
        return;
    }

    // --- normalize integer inputs ---
    k_detect64<<<1, 64, 0, stream>>>((const long long*)in[15], 64, flag);
    k_cvt_idx<<<(10368 + 255) / 256, 256, 0, stream>>>(in[15], 10368, flag, e0);
    k_cvt_idx<<<(20736 + 255) / 256, 256, 0, stream>>>(in[16], 20736, flag, e1);
    k_cvt_idx<<<(41472 + 255) / 256, 256, 0, stream>>>(in[17], 41472, flag, e2);
    k_cvt_idx<<<(82944 + 255) / 256, 256, 0, stream>>>(in[18], 82944, flag, e3);
    k_cvt_idx<<<(6912 + 255) / 256, 256, 0, stream>>>(in[19], 6912, flag, pm);

    // FC1 + FC2
    k_fc1<<<dim3(2, 128), 256, 0, stream>>>(x, fc_w1, fc_b1, h1);
    k_fc2_gemm3<<<1728, 256, 0, stream>>>(h1, fc_w2, fc_b2, buf0);

    auto build = [&](const int* edge, int e, int n) {
        int nb_n = (n + 255) / 256, nb_e = (e + 255) / 256;
        k_zero_int<<<nb_n, 256, 0, stream>>>(ideg, n);
        k_zero_int<<<nb_n, 256, 0, stream>>>(cnt, n);
        k_deg<<<nb_e, 256, 0, stream>>>(edge + e, e, ideg);
        k_dinv<<<nb_n, 256, 0, stream>>>(ideg, dinv, n);
        k_scan<<<1, 256, 0, stream>>>(ideg, rowp, n);
        k_fill<<<nb_e, 256, 0, stream>>>(edge, edge + e, e, rowp, cnt, dinv, col, val);
    };

    // Layer 0: n=864, ci=128, co=128 -> repeat to 1728 (MT=64 -> 1728 blocks)
    build(e0, 6 * 864, 864);
    k_prop2<128, 0><<<dim3(864, 16), dim3(32, 8), 0, stream>>>(buf0, buf0, rowp, col, val, buf1, 864);
    k_prop2<128, 1><<<dim3(864, 16), dim3(32, 8), 0, stream>>>(buf1, buf0, rowp, col, val, buf2, 864);
    k_cheb_gemm3<128, 128, true><<<1728, 256, 0, stream>>>(buf0, buf1, buf2, W0, b0, buf3, 864);

    // Layer 1: n=1728, ci=128, co=64 -> repeat to 3456 (MT=128 -> 1728 blocks)
    build(e1, 6 * 1728, 1728);
    k_prop2<128, 0><<<dim3(1728, 16), dim3(32, 8), 0, stream>>>(buf3, buf3, rowp, col, val, buf1, 1728);
    k_prop2<128, 1><<<dim3(1728, 16), dim3(32, 8), 0, stream>>>(buf1, buf3, rowp, col, val, buf2, 1728);
    k_cheb_gemm3<128, 64, true><<<1728, 256, 0, stream>>>(buf3, buf1, buf2, W1, b1, buf0, 1728);

    // Layer 2: n=3456, ci=64, co=32 -> repeat to 6912 (MT=256 -> 1728 blocks)
    build(e2, 6 * 3456, 3456);
    k_prop2<64, 0><<<dim3(3456, 8), dim3(16, 16), 0, stream>>>(buf0, buf0, rowp, col, val, buf1, 3456);
    k_prop2<64, 1><<<dim3(3456, 8), dim3(16, 16), 0, stream>>>(buf1, buf0, rowp, col, val, buf2, 3456);
    k_cheb_gemm3<64, 32, true><<<1728, 256, 0, stream>>>(buf0, buf1, buf2, W2, b2, buf3, 3456);

    // Layer 3: n=6912, ci=32, co=16, lrelu, NO repeat
    build(e3, 6 * 6912, 6912);
    k_prop2<32, 0><<<dim3(6912, 4), dim3(8, 32), 0, stream>>>(buf3, buf3, rowp, col, val, buf1, 6912);
    k_prop2<32, 1><<<dim3(6912, 4), dim3(8, 32), 0, stream>>>(buf1, buf3, rowp, col, val, buf2, 6912);
    k_cheb_gemm2<32, 16, false><<<3456, 256, 0, stream>>>(buf3, buf1, buf2, W3, b3, buf0, 6912);

    // Layer 4: n=6912, ci=16, co=3
    k_prop2<16, 0><<<dim3(6912, 2), dim3(4, 64), 0, stream>>>(buf0, buf0, rowp, col, val, buf1, 6912);
    k_prop2<16, 1><<<dim3(6912, 2), dim3(4, 64), 0, stream>>>(buf1, buf0, rowp, col, val, buf2, 6912);
    k_final_conv<<<(884736 + 255) / 256, 256, 0, stream>>>(buf0, buf1, buf2, W4, b4, buf3, 884736);

    // Permute + slice, f32 output
    int tot = 128 * 6890 * 3;
    k_permute<<<(tot + 255) / 256, 256, 0, stream>>>(buf3, pm, out);

    if (!map_ok) k_signal<<<1, 64, 0, stream>>>(out, 2000.0f);
}